// Round 7
// baseline (346.345 us; speedup 1.0000x reference)
//
#include <hip/hip_runtime.h>

// Actor_att1 on gfx950 — R13: 64 rows/wave, dual row-group chains.
// One wave = 64 rows (two 32-row groups n and n+32 sharing A-fragments).
// 32x32x16 f16 MFMA. B layout: n=lane&31, k=8*(lane>>5)+j.
// D layout: m=(r&3)+8*(r>>2)+4h. L1 output channels permuted by bitswap23(m).
// Rationale (R12 counters): VALU -23% moved the wall only 3% -> not
// issue-bound; per-wave wall ~100k cyc vs ~6k issue -> the 31-step serial
// softmax chain dominates. Halve steps/row + 4 independent chains/step.
// Blocks: 2 waves x 64 rows, LDS 52KB -> 3 blocks/CU.

#define OBS 127
#define RSTR 200            // f16 per row: 400 B, 16B-aligned
#define ZROW (64 * RSTR)    // zero row (f16 idx) within a wave's region
#define WWORDS (65 * RSTR)  // 13000 f16 per wave

typedef _Float16 v8h  __attribute__((ext_vector_type(8)));
typedef _Float16 v8ha __attribute__((ext_vector_type(8), aligned(16)));
typedef float    f32x8 __attribute__((ext_vector_type(8)));
typedef float    v16f __attribute__((ext_vector_type(16)));
typedef float    f4u  __attribute__((ext_vector_type(4), aligned(4)));
typedef float    f2u  __attribute__((ext_vector_type(2), aligned(4)));
typedef unsigned ui2  __attribute__((ext_vector_type(2), aligned(8)));
typedef unsigned ui4  __attribute__((ext_vector_type(4), aligned(16)));

#define MFMA16(a, b, c) __builtin_amdgcn_mfma_f32_32x32x16_f16((a), (b), (c), 0, 0, 0)

__device__ __forceinline__ unsigned pkw(float a, float b) {
    return __builtin_bit_cast(unsigned, __builtin_amdgcn_cvt_pkrtz(a, b));
}
__device__ __forceinline__ v8h zero8h() {
    v8h z;
    #pragma unroll
    for (int j = 0; j < 8; ++j) z[j] = (_Float16)0.f;
    return z;
}
__device__ __forceinline__ v8h pk8(const v16f& d, int b) {
    ui4 u;
    u[0] = pkw(d[b],     d[b + 1]);
    u[1] = pkw(d[b + 2], d[b + 3]);
    u[2] = pkw(d[b + 4], d[b + 5]);
    u[3] = pkw(d[b + 6], d[b + 7]);
    return __builtin_bit_cast(v8h, u);
}
__device__ __forceinline__ v8h pkr8(const v16f& d, int b) {
    return __builtin_elementwise_max(pk8(d, b), zero8h());
}
__device__ __forceinline__ v8h pk8v(f32x8 v) {
    ui4 u;
    u[0] = pkw(v[0], v[1]);
    u[1] = pkw(v[2], v[3]);
    u[2] = pkw(v[4], v[5]);
    u[3] = pkw(v[6], v[7]);
    return __builtin_bit_cast(v8h, u);
}
__device__ __forceinline__ v8h lrelu8(v8h t) {
    const v8h s = t * (_Float16)0.01f;
    return __builtin_elementwise_max(t, s);
}
// L1 A-frag: output ch permuted by bitswap23; bias row at k==kin.
__device__ __forceinline__ v8h a1fragK16(const float* __restrict__ W,
                                         const float* __restrict__ b,
                                         int kin, int m, int h) {
    const int Lm = (m & ~12) | ((m & 4) << 1) | ((m & 8) >> 1);
    v8h r;
    #pragma unroll
    for (int j = 0; j < 8; ++j) {
        const int k = 8 * h + j;
        const float v = (k < kin) ? W[k * 32 + Lm] : (k == kin ? b[Lm] : 0.f);
        r[j] = (_Float16)v;
    }
    return r;
}
// L2 A chunk s: pairs with B logical ch 16s+8h+j (W2 is 32x16).
__device__ __forceinline__ v8h a2fragK16(const float* __restrict__ W2,
                                         int s, int m, int h) {
    v8h r;
    #pragma unroll
    for (int j = 0; j < 8; ++j)
        r[j] = (_Float16)((m < 16) ? W2[(16 * s + 8 * h + j) * 16 + m] : 0.f);
    return r;
}
// merge A chunk: B position (h,j) holds source ch base+(j&3)+8*(j>>2)+4h.
__device__ __forceinline__ v8h mfragK16(const float* __restrict__ W, int ncols,
                                        int base, int m, int h, int colmax) {
    v8h r;
    #pragma unroll
    for (int j = 0; j < 8; ++j) {
        const int ch = base + (j & 3) + 8 * (j >> 2) + 4 * h;
        r[j] = (_Float16)((m < colmax) ? W[ch * ncols + m] : 0.f);
    }
    return r;
}
__device__ __forceinline__ float fast_tanh(float x) {
    x = fminf(fmaxf(x, -15.f), 15.f);
    const float ex = __expf(2.f * x);
    return (ex - 1.f) / (ex + 1.f);
}

__device__ __forceinline__ v8h ld16h(const _Float16* p) {
    return *(const v8ha*)p;
}
__device__ __forceinline__ v8h ld8h(const _Float16* p) {
    const ui2 w = *(const ui2*)p;
    ui4 u;
    u[0] = w[0]; u[1] = w[1]; u[2] = 0u; u[3] = 0u;
    return __builtin_bit_cast(v8h, u);
}

// Dual-group entity step: 2 independent L1->pack->L2 chains + softmax accum.
__device__ __forceinline__ void estep2(v8h bf0, v8h bf1,
                                       v8h A1, v8h A2a, v8h A2b,
                                       f32x8 b2v, f32x8 stl0, f32x8 stl1,
                                       float& l0, f32x8& o0,
                                       float& l1, f32x8& o1, v16f z16) {
    const v16f dH0 = MFMA16(A1, bf0, z16);
    const v16f dH1 = MFMA16(A1, bf1, z16);
    const v8h p00 = pkr8(dH0, 0);
    const v8h p01 = pkr8(dH0, 8);
    const v8h p10 = pkr8(dH1, 0);
    const v8h p11 = pkr8(dH1, 8);
    v16f c0 = MFMA16(A2a, p00, z16);
    c0 = MFMA16(A2b, p01, c0);
    v16f c1 = MFMA16(A2a, p10, z16);
    c1 = MFMA16(A2b, p11, c1);
    f32x8 e20, e21;
    #pragma unroll
    for (int r = 0; r < 8; ++r) e20[r] = fmaxf(c0[r] + b2v[r], 0.f);
    #pragma unroll
    for (int r = 0; r < 8; ++r) e21[r] = fmaxf(c1[r] + b2v[r], 0.f);
    float d0 = 0.f, d1 = 0.f;
    #pragma unroll
    for (int r = 0; r < 8; ++r) { d0 += stl0[r] * e20[r]; d1 += stl1[r] * e21[r]; }
    d0 += __shfl_xor(d0, 32);
    d1 += __shfl_xor(d1, 32);
    const float p0 = __builtin_amdgcn_exp2f(d0);
    const float p1 = __builtin_amdgcn_exp2f(d1);
    l0 += p0; o0 += p0 * e20;
    l1 += p1; o1 += p1 * e21;
}

// normalize + LayerNorm(16) + affine + relu -> packed merge B chunk
__device__ __forceinline__ v8h ln_fin(float l, f32x8 o, f32x8 gv, f32x8 blv) {
    const float rl = 1.f / l;
    f32x8 a = o * rl;
    float sum = 0.f;
    #pragma unroll
    for (int r = 0; r < 8; ++r) sum += a[r];
    sum += __shfl_xor(sum, 32);
    const float mu = sum * 0.0625f;
    a -= mu;
    float var = 0.f;
    #pragma unroll
    for (int r = 0; r < 8; ++r) var += a[r] * a[r];
    var += __shfl_xor(var, 32);
    const float inv = rsqrtf(var * 0.0625f + 1e-5f);
    f32x8 v;
    #pragma unroll
    for (int r = 0; r < 8; ++r) v[r] = fmaxf(a[r] * inv * gv[r] + blv[r], 0.f);
    return pk8v(v);
}

__global__ __launch_bounds__(128, 2)
void actor_mfma(const float* __restrict__ x,
                const float* __restrict__ en_w1, const float* __restrict__ en_b1,
                const float* __restrict__ en_w2, const float* __restrict__ en_b2,
                const float* __restrict__ oa_w1, const float* __restrict__ oa_b1,
                const float* __restrict__ oa_w2, const float* __restrict__ oa_b2,
                const float* __restrict__ oa_g,  const float* __restrict__ oa_bln,
                const float* __restrict__ g_w1,  const float* __restrict__ g_b1,
                const float* __restrict__ g_w2,  const float* __restrict__ g_b2,
                const float* __restrict__ g_g,   const float* __restrict__ g_bln,
                const float* __restrict__ m_w1,  const float* __restrict__ m_b1,
                const float* __restrict__ m_w2,  const float* __restrict__ m_b2,
                const float* __restrict__ m_w3,  const float* __restrict__ m_b3,
                float* __restrict__ out, int B)
{
    const int lane = threadIdx.x & 63, wid = threadIdx.x >> 6;
    const int n = lane & 31, h = lane >> 5;

    __shared__ __align__(16) _Float16 xs_all[2][WWORDS];
    _Float16* xs = xs_all[wid];

    const int r0 = blockIdx.x * 128 + wid * 64;
    int rows = B - r0;
    rows = rows > 64 ? 64 : (rows < 0 ? 0 : rows);

    // ---- zero row (serves h==1 lanes' B-fragment reads) ----
    if (lane < 24) {
        ui4 z;
        z[0] = 0u; z[1] = 0u; z[2] = 0u; z[3] = 0u;
        *(ui4*)(xs + ZROW + lane * 8) = z;
    }

    // ---- stage 64 rows into entity-packed f16 layout ----
    // row base + [0..7]   : x0,x1,x2,x3,1,0,0,0            (self, b128)
    // row base + [8+4e]   : f0,f1,f2,1                     (food e, b64)
    // row base + [72+8e]  : px,py,vx,vy,scal,1,0,0         (other e, b128)
    if (rows > 0) {
        const float* __restrict__ xp = x + (size_t)r0 * OBS;
        if (lane < rows) {                       // self: one row per lane
            const f4u v = *(const f4u*)(xp + lane * OBS);
            ui4 q;
            q[0] = pkw(v[0], v[1]);
            q[1] = pkw(v[2], v[3]);
            q[2] = pkw(1.f, 0.f);
            q[3] = 0u;
            *(ui4*)(xs + lane * RSTR) = q;
        }
        #pragma unroll
        for (int i = 0; i < 16; ++i) {           // food: 64 rows x 16 entities
            const int t = i * 64 + lane, row = t >> 4, e = t & 15;
            if (row < rows) {
                const f4u v = *(const f4u*)(xp + row * OBS + 78 + 3 * e);
                ui2 w;
                w[0] = pkw(v[1], v[2]);
                w[1] = pkw(v[3], 1.f);
                *(ui2*)(xs + row * RSTR + 8 + 4 * e) = w;
            }
        }
        #pragma unroll
        for (int i = 0; i < 16; ++i) {           // other: 64 rows x 15 entities
            const int t = i * 64 + lane, row = t >> 4, e = t & 15;
            if (e < 15 && row < rows) {
                const float* rp = xp + row * OBS;
                const f2u pv = *(const f2u*)(rp + 4 + 2 * e);
                const f2u vv = *(const f2u*)(rp + 34 + 2 * e);
                const float sc = rp[64 + e];
                ui4 q;
                q[0] = pkw(pv[0], pv[1]);
                q[1] = pkw(vv[0], vv[1]);
                q[2] = pkw(sc, 1.f);
                q[3] = 0u;
                *(ui4*)(xs + row * RSTR + 72 + 8 * e) = q;
            }
        }
    }
    // no __syncthreads: each wave reads only its own LDS region.

    v16f z16;
    #pragma unroll
    for (int r = 0; r < 16; ++r) z16[r] = 0.f;

    f32x8 sb2v, fb2v, ob2v;
    #pragma unroll
    for (int r = 0; r < 8; ++r) {
        const int m = (r & 3) + 8 * (r >> 2) + 4 * h;
        sb2v[r] = en_b2[m];
        fb2v[r] = g_b2[m];
        ob2v[r] = oa_b2[m];
    }

    const int rb0 = h ? ZROW : n * RSTR;
    const int rb1 = h ? ZROW : (n + 32) * RSTR;

    f32x8 stl0, stl1;
    v8h Bs0, Bs1;
    {   // ---- self encoder (dual) ----
        const v8h sA1 = a1fragK16(en_w1, en_b1, 4, n, h);
        const v8h sA2a = a2fragK16(en_w2, 0, n, h);
        const v8h sA2b = a2fragK16(en_w2, 1, n, h);
        const v8h bs0 = ld16h(xs + rb0);
        const v8h bs1 = ld16h(xs + rb1);
        const v16f dS0 = MFMA16(sA1, bs0, z16);
        const v16f dS1 = MFMA16(sA1, bs1, z16);
        v16f cS0 = MFMA16(sA2a, pkr8(dS0, 0), z16);
        cS0 = MFMA16(sA2b, pkr8(dS0, 8), cS0);
        v16f cS1 = MFMA16(sA2a, pkr8(dS1, 0), z16);
        cS1 = MFMA16(sA2b, pkr8(dS1, 8), cS1);
        const float SK = 0.25f * 1.44269504088896f;   // (1/4)*log2(e)
        f32x8 sv0, sv1;
        #pragma unroll
        for (int r = 0; r < 8; ++r) sv0[r] = fmaxf(cS0[r] + sb2v[r], 0.f);
        #pragma unroll
        for (int r = 0; r < 8; ++r) sv1[r] = fmaxf(cS1[r] + sb2v[r], 0.f);
        stl0 = sv0 * SK;
        stl1 = sv1 * SK;
        Bs0 = pk8v(sv0);
        Bs1 = pk8v(sv1);
    }

    // ---- fused entity loop: 4 independent chains per step ----
    v8h fA1 = a1fragK16(g_w1, g_b1, 3, n, h);
    v8h fA2a = a2fragK16(g_w2, 0, n, h);
    v8h fA2b = a2fragK16(g_w2, 1, n, h);
    v8h oA1 = a1fragK16(oa_w1, oa_b1, 5, n, h);
    v8h oA2a = a2fragK16(oa_w2, 0, n, h);
    v8h oA2b = a2fragK16(oa_w2, 1, n, h);

    float lf0 = 0.f, lf1 = 0.f, lo0 = 0.f, lo1 = 0.f;
    f32x8 of0 = 0.f, of1 = 0.f, oo0 = 0.f, oo1 = 0.f;
    #pragma unroll 2
    for (int e = 0; e < 16; ++e) {
        // Anti-remat pin: keep invariant fragments register-resident.
        asm volatile("" : "+v"(fA1), "+v"(fA2a), "+v"(fA2b),
                          "+v"(oA1), "+v"(oA2a), "+v"(oA2b));
        asm volatile("" : "+v"(fb2v), "+v"(ob2v), "+v"(z16));
        const v8h bfF0 = ld8h(xs + rb0 + 8 + 4 * e);
        const v8h bfF1 = ld8h(xs + rb1 + 8 + 4 * e);
        estep2(bfF0, bfF1, fA1, fA2a, fA2b, fb2v, stl0, stl1,
               lf0, of0, lf1, of1, z16);
        if (e < 15) {
            const v8h bfO0 = ld16h(xs + rb0 + 72 + 8 * e);
            const v8h bfO1 = ld16h(xs + rb1 + 72 + 8 * e);
            estep2(bfO0, bfO1, oA1, oA2a, oA2b, ob2v, stl0, stl1,
                   lo0, oo0, lo1, oo1, z16);
        }
    }

    // ---- finalize branches ----
    f32x8 fgv, fblv, ogv, oblv;
    #pragma unroll
    for (int r = 0; r < 8; ++r) {
        const int m = (r & 3) + 8 * (r >> 2) + 4 * h;
        fgv[r] = g_g[m];  fblv[r] = g_bln[m];
        ogv[r] = oa_g[m]; oblv[r] = oa_bln[m];
    }
    const v8h Bf0 = ln_fin(lf0, of0, fgv, fblv);
    const v8h Bf1 = ln_fin(lf1, of1, fgv, fblv);
    const v8h Bo0 = ln_fin(lo0, oo0, ogv, oblv);
    const v8h Bo1 = ln_fin(lo1, oo1, ogv, oblv);

    // ---- merge MLP (dual): 48 -> 32 lrelu -> 32 lrelu -> 2 tanh ----
    v16f m1C, m2C;
    #pragma unroll
    for (int r = 0; r < 16; ++r) {
        const int m = (r & 3) + 8 * (r >> 2) + 4 * h;
        m1C[r] = m_b1[m];
        m2C[r] = m_b2[m];
    }
    const v8h w1a = mfragK16(m_w1, 32, 0, n, h, 32);
    const v8h w1b = mfragK16(m_w1, 32, 16, n, h, 32);
    const v8h w1c = mfragK16(m_w1, 32, 32, n, h, 32);
    v16f m1a = MFMA16(w1a, Bs0, m1C);
    m1a = MFMA16(w1b, Bf0, m1a);
    m1a = MFMA16(w1c, Bo0, m1a);
    v16f m1b = MFMA16(w1a, Bs1, m1C);
    m1b = MFMA16(w1b, Bf1, m1b);
    m1b = MFMA16(w1c, Bo1, m1b);
    const v8h w2a = mfragK16(m_w2, 32, 0, n, h, 32);
    const v8h w2b = mfragK16(m_w2, 32, 16, n, h, 32);
    v16f m2a = MFMA16(w2a, lrelu8(pk8(m1a, 0)), m2C);
    m2a = MFMA16(w2b, lrelu8(pk8(m1a, 8)), m2a);
    v16f m2b = MFMA16(w2a, lrelu8(pk8(m1b, 0)), m2C);
    m2b = MFMA16(w2b, lrelu8(pk8(m1b, 8)), m2b);
    const v8h w3a = mfragK16(m_w3, 2, 0, n, h, 2);
    const v8h w3b = mfragK16(m_w3, 2, 16, n, h, 2);
    v16f m3a = MFMA16(w3a, lrelu8(pk8(m2a, 0)), z16);
    m3a = MFMA16(w3b, lrelu8(pk8(m2a, 8)), m3a);
    v16f m3b = MFMA16(w3a, lrelu8(pk8(m2b, 0)), z16);
    m3b = MFMA16(w3b, lrelu8(pk8(m2b, 8)), m3b);

    if (h == 0 && n < rows) {
        float2 res;
        res.x = fast_tanh(m3a[0] + m_b3[0]);
        res.y = fast_tanh(m3a[1] + m_b3[1]);
        *(float2*)(out + (size_t)(r0 + n) * 2) = res;
    }
    if (h == 0 && 32 + n < rows) {
        float2 res;
        res.x = fast_tanh(m3b[0] + m_b3[0]);
        res.y = fast_tanh(m3b[1] + m_b3[1]);
        *(float2*)(out + (size_t)(r0 + 32 + n) * 2) = res;
    }
}

extern "C" void kernel_launch(void* const* d_in, const int* in_sizes, int n_in,
                              void* d_out, int out_size, void* d_ws, size_t ws_size,
                              hipStream_t stream) {
    const int B = in_sizes[0] / OBS;
    const float* xin = (const float*)d_in[0];
    const float* en_w1 = (const float*)d_in[1];
    const float* en_b1 = (const float*)d_in[2];
    const float* en_w2 = (const float*)d_in[3];
    const float* en_b2 = (const float*)d_in[4];
    const float* oa_w1 = (const float*)d_in[5];
    const float* oa_b1 = (const float*)d_in[6];
    const float* oa_w2 = (const float*)d_in[7];
    const float* oa_b2 = (const float*)d_in[8];
    const float* oa_g  = (const float*)d_in[9];
    const float* oa_bl = (const float*)d_in[10];
    const float* g_w1  = (const float*)d_in[11];
    const float* g_b1  = (const float*)d_in[12];
    const float* g_w2  = (const float*)d_in[13];
    const float* g_b2  = (const float*)d_in[14];
    const float* g_g   = (const float*)d_in[15];
    const float* g_bl  = (const float*)d_in[16];
    const float* m_w1  = (const float*)d_in[17];
    const float* m_b1  = (const float*)d_in[18];
    const float* m_w2  = (const float*)d_in[19];
    const float* m_b2  = (const float*)d_in[20];
    const float* m_w3  = (const float*)d_in[21];
    const float* m_b3  = (const float*)d_in[22];

    const int rows_per_block = 128;  // 2 waves x 64 rows
    const int grid = (B + rows_per_block - 1) / rows_per_block;
    actor_mfma<<<grid, 128, 0, stream>>>(
        xin, en_w1, en_b1, en_w2, en_b2,
        oa_w1, oa_b1, oa_w2, oa_b2, oa_g, oa_bl,
        g_w1, g_b1, g_w2, g_b2, g_g, g_bl,
        m_w1, m_b1, m_w2, m_b2, m_w3, m_b3,
        (float*)d_out, B);
}

// Round 8
// 304.723 us; speedup vs baseline: 1.1366x; 1.1366x over previous
//
#include <hip/hip_runtime.h>

// Actor_att1 on gfx950 — R14: dual-chain (food/other) interleaved entity loop
// inside the R12 occupancy envelope (32 rows/wave, 4 waves/block, 12 waves/CU).
// 32x32x16 f16 MFMA. B layout: n=lane&31, k=8*(lane>>5)+j.
// D layout: m=(r&3)+8*(r>>2)+4h. L1 output channels permuted by bitswap23(m).
// Evidence: R13 proved manual chain-interleave cuts per-row latency 1.35x
// (VGPR 120) but its 64-row waves halved resident waves (52KB LDS @ 128thr).
// R14 pairs O(e) with F(e+1) — independent chains in the SAME 32 rows —
// prologue F(0), 15 paired iterations. Pins now non-volatile (anti-remat
// without a scheduling barrier). Tree-reduced softmax dot (depth 4).

#define OBS 127
#define RSTR 200            // f16 per row: 400 B, 16B-aligned
#define ZROW (32 * RSTR)    // zero row (f16 idx) within a wave's region
#define WWORDS (33 * RSTR)  // 6600 f16 per wave

typedef _Float16 v8h  __attribute__((ext_vector_type(8)));
typedef _Float16 v8ha __attribute__((ext_vector_type(8), aligned(16)));
typedef float    f32x8 __attribute__((ext_vector_type(8)));
typedef float    v16f __attribute__((ext_vector_type(16)));
typedef float    f4u  __attribute__((ext_vector_type(4), aligned(4)));
typedef float    f2u  __attribute__((ext_vector_type(2), aligned(4)));
typedef unsigned ui2  __attribute__((ext_vector_type(2), aligned(8)));
typedef unsigned ui4  __attribute__((ext_vector_type(4), aligned(16)));

#define MFMA16(a, b, c) __builtin_amdgcn_mfma_f32_32x32x16_f16((a), (b), (c), 0, 0, 0)

__device__ __forceinline__ unsigned pkw(float a, float b) {
    return __builtin_bit_cast(unsigned, __builtin_amdgcn_cvt_pkrtz(a, b));
}
__device__ __forceinline__ v8h zero8h() {
    v8h z;
    #pragma unroll
    for (int j = 0; j < 8; ++j) z[j] = (_Float16)0.f;
    return z;
}
__device__ __forceinline__ v8h pk8(const v16f& d, int b) {
    ui4 u;
    u[0] = pkw(d[b],     d[b + 1]);
    u[1] = pkw(d[b + 2], d[b + 3]);
    u[2] = pkw(d[b + 4], d[b + 5]);
    u[3] = pkw(d[b + 6], d[b + 7]);
    return __builtin_bit_cast(v8h, u);
}
__device__ __forceinline__ v8h pkr8(const v16f& d, int b) {
    return __builtin_elementwise_max(pk8(d, b), zero8h());
}
__device__ __forceinline__ v8h pk8v(f32x8 v) {
    ui4 u;
    u[0] = pkw(v[0], v[1]);
    u[1] = pkw(v[2], v[3]);
    u[2] = pkw(v[4], v[5]);
    u[3] = pkw(v[6], v[7]);
    return __builtin_bit_cast(v8h, u);
}
__device__ __forceinline__ v8h lrelu8(v8h t) {
    const v8h s = t * (_Float16)0.01f;
    return __builtin_elementwise_max(t, s);
}
// L1 A-frag: output ch permuted by bitswap23; bias row at k==kin.
__device__ __forceinline__ v8h a1fragK16(const float* __restrict__ W,
                                         const float* __restrict__ b,
                                         int kin, int m, int h) {
    const int Lm = (m & ~12) | ((m & 4) << 1) | ((m & 8) >> 1);
    v8h r;
    #pragma unroll
    for (int j = 0; j < 8; ++j) {
        const int k = 8 * h + j;
        const float v = (k < kin) ? W[k * 32 + Lm] : (k == kin ? b[Lm] : 0.f);
        r[j] = (_Float16)v;
    }
    return r;
}
// L2 A chunk s: pairs with B logical ch 16s+8h+j (W2 is 32x16).
__device__ __forceinline__ v8h a2fragK16(const float* __restrict__ W2,
                                         int s, int m, int h) {
    v8h r;
    #pragma unroll
    for (int j = 0; j < 8; ++j)
        r[j] = (_Float16)((m < 16) ? W2[(16 * s + 8 * h + j) * 16 + m] : 0.f);
    return r;
}
// merge A chunk: B position (h,j) holds source ch base+(j&3)+8*(j>>2)+4h.
__device__ __forceinline__ v8h mfragK16(const float* __restrict__ W, int ncols,
                                        int base, int m, int h, int colmax) {
    v8h r;
    #pragma unroll
    for (int j = 0; j < 8; ++j) {
        const int ch = base + (j & 3) + 8 * (j >> 2) + 4 * h;
        r[j] = (_Float16)((m < colmax) ? W[ch * ncols + m] : 0.f);
    }
    return r;
}
__device__ __forceinline__ float fast_tanh(float x) {
    x = fminf(fmaxf(x, -15.f), 15.f);
    const float ex = __expf(2.f * x);
    return (ex - 1.f) / (ex + 1.f);
}

__device__ __forceinline__ v8h ld16h(const _Float16* p) {
    return *(const v8ha*)p;
}
__device__ __forceinline__ v8h ld8h(const _Float16* p) {
    const ui2 w = *(const ui2*)p;
    ui4 u;
    u[0] = w[0]; u[1] = w[1]; u[2] = 0u; u[3] = 0u;
    return __builtin_bit_cast(v8h, u);
}
// tree dot: depth ~4 (mul, fma, add, add) vs 8-deep fma chain
__device__ __forceinline__ float dot8(f32x8 a, f32x8 b) {
    float s0 = a[0] * b[0], s1 = a[1] * b[1];
    float s2 = a[2] * b[2], s3 = a[3] * b[3];
    s0 += a[4] * b[4]; s1 += a[5] * b[5];
    s2 += a[6] * b[6]; s3 += a[7] * b[7];
    return (s0 + s1) + (s2 + s3);
}

// normalize + LayerNorm(16) + affine + relu -> packed merge B chunk
__device__ __forceinline__ v8h ln_fin(float l, f32x8 o, f32x8 gv, f32x8 blv) {
    const float rl = 1.f / l;
    f32x8 a = o * rl;
    float sum = 0.f;
    #pragma unroll
    for (int r = 0; r < 8; ++r) sum += a[r];
    sum += __shfl_xor(sum, 32);
    const float mu = sum * 0.0625f;
    a -= mu;
    float var = 0.f;
    #pragma unroll
    for (int r = 0; r < 8; ++r) var += a[r] * a[r];
    var += __shfl_xor(var, 32);
    const float inv = rsqrtf(var * 0.0625f + 1e-5f);
    f32x8 v;
    #pragma unroll
    for (int r = 0; r < 8; ++r) v[r] = fmaxf(a[r] * inv * gv[r] + blv[r], 0.f);
    return pk8v(v);
}

__global__ __launch_bounds__(256, 3)
void actor_mfma(const float* __restrict__ x,
                const float* __restrict__ en_w1, const float* __restrict__ en_b1,
                const float* __restrict__ en_w2, const float* __restrict__ en_b2,
                const float* __restrict__ oa_w1, const float* __restrict__ oa_b1,
                const float* __restrict__ oa_w2, const float* __restrict__ oa_b2,
                const float* __restrict__ oa_g,  const float* __restrict__ oa_bln,
                const float* __restrict__ g_w1,  const float* __restrict__ g_b1,
                const float* __restrict__ g_w2,  const float* __restrict__ g_b2,
                const float* __restrict__ g_g,   const float* __restrict__ g_bln,
                const float* __restrict__ m_w1,  const float* __restrict__ m_b1,
                const float* __restrict__ m_w2,  const float* __restrict__ m_b2,
                const float* __restrict__ m_w3,  const float* __restrict__ m_b3,
                float* __restrict__ out, int B)
{
    const int lane = threadIdx.x & 63, wid = threadIdx.x >> 6;
    const int n = lane & 31, h = lane >> 5;

    __shared__ __align__(16) _Float16 xs_all[4][WWORDS];
    _Float16* xs = xs_all[wid];

    const int r0 = blockIdx.x * 128 + wid * 32;
    int rows = B - r0;
    rows = rows > 32 ? 32 : (rows < 0 ? 0 : rows);

    // ---- zero row (serves h==1 lanes' B-fragment reads) ----
    if (lane < 24) {
        ui4 z;
        z[0] = 0u; z[1] = 0u; z[2] = 0u; z[3] = 0u;
        *(ui4*)(xs + ZROW + lane * 8) = z;
    }

    // ---- stage rows into entity-packed f16 layout ----
    // row base + [0..7]   : x0,x1,x2,x3,1,0,0,0            (self, b128)
    // row base + [8+4e]   : f0,f1,f2,1                     (food e, b64)
    // row base + [72+8e]  : px,py,vx,vy,scal,1,0,0         (other e, b128)
    if (rows > 0) {
        const float* __restrict__ xp = x + (size_t)r0 * OBS;
        if (lane < rows) {                       // self, one row per lane
            const f4u v = *(const f4u*)(xp + lane * OBS);
            ui4 q;
            q[0] = pkw(v[0], v[1]);
            q[1] = pkw(v[2], v[3]);
            q[2] = pkw(1.f, 0.f);
            q[3] = 0u;
            *(ui4*)(xs + lane * RSTR) = q;
        }
        #pragma unroll
        for (int i = 0; i < 8; ++i) {            // food: 32 rows x 16 entities
            const int t = i * 64 + lane, row = t >> 4, e = t & 15;
            if (row < rows) {
                const f4u v = *(const f4u*)(xp + row * OBS + 78 + 3 * e);
                ui2 w;
                w[0] = pkw(v[1], v[2]);
                w[1] = pkw(v[3], 1.f);
                *(ui2*)(xs + row * RSTR + 8 + 4 * e) = w;
            }
        }
        #pragma unroll
        for (int i = 0; i < 8; ++i) {            // other: 32 rows x 15 entities
            const int t = i * 64 + lane, row = t >> 4, e = t & 15;
            if (e < 15 && row < rows) {
                const float* rp = xp + row * OBS;
                const f2u pv = *(const f2u*)(rp + 4 + 2 * e);
                const f2u vv = *(const f2u*)(rp + 34 + 2 * e);
                const float sc = rp[64 + e];
                ui4 q;
                q[0] = pkw(pv[0], pv[1]);
                q[1] = pkw(vv[0], vv[1]);
                q[2] = pkw(sc, 1.f);
                q[3] = 0u;
                *(ui4*)(xs + row * RSTR + 72 + 8 * e) = q;
            }
        }
    }
    // no __syncthreads: each wave reads only its own LDS region.

    v16f z16;
    #pragma unroll
    for (int r = 0; r < 16; ++r) z16[r] = 0.f;

    f32x8 sb2v, fb2v, ob2v;
    #pragma unroll
    for (int r = 0; r < 8; ++r) {
        const int m = (r & 3) + 8 * (r >> 2) + 4 * h;
        sb2v[r] = en_b2[m];
        fb2v[r] = g_b2[m];
        ob2v[r] = oa_b2[m];
    }

    const int rbase = h ? ZROW : n * RSTR;   // h==1 lanes always read zeros

    f32x8 stl;
    v8h Bs;
    {   // ---- self encoder ----
        const v8h sA1 = a1fragK16(en_w1, en_b1, 4, n, h);
        const v8h sA2a = a2fragK16(en_w2, 0, n, h);
        const v8h sA2b = a2fragK16(en_w2, 1, n, h);
        const v8h bs = ld16h(xs + rbase);
        const v16f dS = MFMA16(sA1, bs, z16);
        v16f cS = MFMA16(sA2a, pkr8(dS, 0), z16);
        cS = MFMA16(sA2b, pkr8(dS, 8), cS);
        const float SK = 0.25f * 1.44269504088896f;   // (1/4)*log2(e)
        f32x8 sv;
        #pragma unroll
        for (int r = 0; r < 8; ++r) sv[r] = fmaxf(cS[r] + sb2v[r], 0.f);
        stl = sv * SK;
        Bs = pk8v(sv);
    }

    // ---- fused entity loop: F(0) prologue, then O(e) || F(e+1) pairs ----
    v8h fA1 = a1fragK16(g_w1, g_b1, 3, n, h);
    v8h fA2a = a2fragK16(g_w2, 0, n, h);
    v8h fA2b = a2fragK16(g_w2, 1, n, h);
    v8h oA1 = a1fragK16(oa_w1, oa_b1, 5, n, h);
    v8h oA2a = a2fragK16(oa_w2, 0, n, h);
    v8h oA2b = a2fragK16(oa_w2, 1, n, h);

    float lf = 0.f, lo = 0.f;
    f32x8 of = 0.f, oo = 0.f;

    {   // F(0) alone
        const v8h bF = ld8h(xs + rbase + 8);
        const v16f dF = MFMA16(fA1, bF, z16);
        v16f cF = MFMA16(fA2a, pkr8(dF, 0), z16);
        cF = MFMA16(fA2b, pkr8(dF, 8), cF);
        f32x8 eF;
        #pragma unroll
        for (int r = 0; r < 8; ++r) eF[r] = fmaxf(cF[r] + fb2v[r], 0.f);
        float pf = dot8(stl, eF);
        pf += __shfl_xor(pf, 32);
        const float p = __builtin_amdgcn_exp2f(pf);
        lf += p;
        of += p * eF;
    }

    #pragma unroll 3
    for (int e = 0; e < 15; ++e) {
        // Anti-remat pin (non-volatile: no scheduling barrier, but the
        // loop-carried "+v" defs make sinking the invariant loads illegal).
        asm("" : "+v"(fA1), "+v"(fA2a), "+v"(fA2b),
                 "+v"(oA1), "+v"(oA2a), "+v"(oA2b));
        asm("" : "+v"(fb2v), "+v"(ob2v), "+v"(z16));
        // two independent chains, hand-interleaved
        const v8h bO = ld16h(xs + rbase + 72 + 8 * e);
        const v8h bF = ld8h(xs + rbase + 8 + 4 * (e + 1));
        const v16f dO = MFMA16(oA1, bO, z16);
        const v16f dF = MFMA16(fA1, bF, z16);
        const v8h pO0 = pkr8(dO, 0);
        const v8h pF0 = pkr8(dF, 0);
        const v8h pO1 = pkr8(dO, 8);
        const v8h pF1 = pkr8(dF, 8);
        v16f cO = MFMA16(oA2a, pO0, z16);
        v16f cF = MFMA16(fA2a, pF0, z16);
        cO = MFMA16(oA2b, pO1, cO);
        cF = MFMA16(fA2b, pF1, cF);
        f32x8 eO, eF;
        #pragma unroll
        for (int r = 0; r < 8; ++r) {
            eO[r] = fmaxf(cO[r] + ob2v[r], 0.f);
            eF[r] = fmaxf(cF[r] + fb2v[r], 0.f);
        }
        float po = dot8(stl, eO);
        float pf = dot8(stl, eF);
        po += __shfl_xor(po, 32);
        pf += __shfl_xor(pf, 32);
        const float eo = __builtin_amdgcn_exp2f(po);
        const float ef = __builtin_amdgcn_exp2f(pf);
        lo += eo;
        lf += ef;
        oo += eo * eO;
        of += ef * eF;
    }

    // ---- finalize branches ----
    f32x8 fgv, fblv, ogv, oblv;
    #pragma unroll
    for (int r = 0; r < 8; ++r) {
        const int m = (r & 3) + 8 * (r >> 2) + 4 * h;
        fgv[r] = g_g[m];  fblv[r] = g_bln[m];
        ogv[r] = oa_g[m]; oblv[r] = oa_bln[m];
    }
    const v8h Bf = ln_fin(lf, of, fgv, fblv);
    const v8h Bo = ln_fin(lo, oo, ogv, oblv);

    // ---- merge MLP: 48 -> 32 lrelu -> 32 lrelu -> 2 tanh ----
    v16f m1C, m2C;
    #pragma unroll
    for (int r = 0; r < 16; ++r) {
        const int m = (r & 3) + 8 * (r >> 2) + 4 * h;
        m1C[r] = m_b1[m];
        m2C[r] = m_b2[m];
    }
    v16f m1 = MFMA16(mfragK16(m_w1, 32, 0, n, h, 32), Bs, m1C);
    m1 = MFMA16(mfragK16(m_w1, 32, 16, n, h, 32), Bf, m1);
    m1 = MFMA16(mfragK16(m_w1, 32, 32, n, h, 32), Bo, m1);
    const v8h q0 = lrelu8(pk8(m1, 0));
    const v8h q1 = lrelu8(pk8(m1, 8));
    v16f m2 = MFMA16(mfragK16(m_w2, 32, 0, n, h, 32), q0, m2C);
    m2 = MFMA16(mfragK16(m_w2, 32, 16, n, h, 32), q1, m2);
    const v8h z0 = lrelu8(pk8(m2, 0));
    const v8h z1 = lrelu8(pk8(m2, 8));
    v16f m3 = MFMA16(mfragK16(m_w3, 2, 0, n, h, 2), z0, z16);
    m3 = MFMA16(mfragK16(m_w3, 2, 16, n, h, 2), z1, m3);

    if (h == 0 && n < rows) {
        float2 res;
        res.x = fast_tanh(m3[0] + m_b3[0]);
        res.y = fast_tanh(m3[1] + m_b3[1]);
        *(float2*)(out + (size_t)(r0 + n) * 2) = res;
    }
}

extern "C" void kernel_launch(void* const* d_in, const int* in_sizes, int n_in,
                              void* d_out, int out_size, void* d_ws, size_t ws_size,
                              hipStream_t stream) {
    const int B = in_sizes[0] / OBS;
    const float* xin = (const float*)d_in[0];
    const float* en_w1 = (const float*)d_in[1];
    const float* en_b1 = (const float*)d_in[2];
    const float* en_w2 = (const float*)d_in[3];
    const float* en_b2 = (const float*)d_in[4];
    const float* oa_w1 = (const float*)d_in[5];
    const float* oa_b1 = (const float*)d_in[6];
    const float* oa_w2 = (const float*)d_in[7];
    const float* oa_b2 = (const float*)d_in[8];
    const float* oa_g  = (const float*)d_in[9];
    const float* oa_bl = (const float*)d_in[10];
    const float* g_w1  = (const float*)d_in[11];
    const float* g_b1  = (const float*)d_in[12];
    const float* g_w2  = (const float*)d_in[13];
    const float* g_b2  = (const float*)d_in[14];
    const float* g_g   = (const float*)d_in[15];
    const float* g_bl  = (const float*)d_in[16];
    const float* m_w1  = (const float*)d_in[17];
    const float* m_b1  = (const float*)d_in[18];
    const float* m_w2  = (const float*)d_in[19];
    const float* m_b2  = (const float*)d_in[20];
    const float* m_w3  = (const float*)d_in[21];
    const float* m_b3  = (const float*)d_in[22];

    const int rows_per_block = 128;  // 4 waves x 32 rows
    const int grid = (B + rows_per_block - 1) / rows_per_block;
    actor_mfma<<<grid, 256, 0, stream>>>(
        xin, en_w1, en_b1, en_w2, en_b2,
        oa_w1, oa_b1, oa_w2, oa_b2, oa_g, oa_bl,
        g_w1, g_b1, g_w2, g_b2, g_g, g_bl,
        m_w1, m_b1, m_w2, m_b2, m_w3, m_b3,
        (float*)d_out, B);
}